// Round 2
// baseline (249.821 us; speedup 1.0000x reference)
//
#include <hip/hip_runtime.h>

// GCN forward on MI355X:
//   out = log_softmax(adj @ (relu(adj @ (x@W1) + b1) @ W2) + b2)
// N=8192, NFEAT=512, NHID=128, NCLASS=40. adj is 256MB f32, read twice.
// bf16 MFMA 16x16x32; adj converted f32->bf16 on the fly through swizzled LDS.
// K-loop: raw s_barrier (NOT __syncthreads -> no vmcnt(0) drain), depth-2
// register prefetch for A (HBM) and B (L2), 2 LDS buffers, 1 barrier/K-tile,
// BM=16 rows/block, 256 threads, grid 512 = 2 blocks/CU.

using bf16x8 = __attribute__((ext_vector_type(8))) __bf16;
using f32x4  = __attribute__((ext_vector_type(4))) float;
using u16x4  = __attribute__((ext_vector_type(4))) unsigned short;

#define NROW 8192
#define KFEAT 512
#define HID 128
#define NCLS 40

__device__ __forceinline__ unsigned short f2b(float f) {
  union { float f; unsigned u; } v; v.f = f;
  unsigned r = v.u + 0x7fffu + ((v.u >> 16) & 1u);
  return (unsigned short)(r >> 16);
}

__device__ __forceinline__ bf16x8 ldb8(const unsigned short* p) {
  return *reinterpret_cast<const bf16x8*>(p);
}

#define KBARRIER()                                        \
  asm volatile("s_waitcnt lgkmcnt(0)" ::: "memory");      \
  __builtin_amdgcn_s_barrier();                           \
  asm volatile("" ::: "memory");                          \
  __builtin_amdgcn_sched_barrier(0)

// One K-tile iteration. T: tile index. AOUT: regs holding A[T+1] (written to
// LDS at end). APRE: regs to receive A[T+2]. BCUR: regs holding B[T] (consumed
// by MFMA, then refilled with B[T+2]).
// LDS bufs: read buf[T&1], write buf[(T+1)&1]; safe with the single barrier
// because all waves sit between the same pair of barriers (disjoint buffers).
#define GITER(T, AOUT, APRE, BCUR)                                             \
  {                                                                            \
    if ((T) + 2 < NT) {                                                        \
      APRE = *reinterpret_cast<const f32x4*>(ap + ((size_t)((T) + 2)) * 64);   \
    }                                                                          \
    const unsigned short* lb = As + (((T) & 1) << 10);                         \
    _Pragma("unroll")                                                          \
    for (int s = 0; s < 2; ++s) {                                              \
      bf16x8 af = *reinterpret_cast<const bf16x8*>(lb + (s ? aoff1 : aoff0));  \
      _Pragma("unroll")                                                        \
      for (int c = 0; c < NC; ++c)                                             \
        acc[c] = __builtin_amdgcn_mfma_f32_16x16x32_bf16(af, BCUR[c][s],       \
                                                         acc[c], 0, 0, 0);    \
    }                                                                          \
    if ((T) + 2 < NT) {                                                        \
      _Pragma("unroll")                                                        \
      for (int c = 0; c < NC; ++c) {                                           \
        BCUR[c][0] = ldb8(bp[c] + ((size_t)((T) + 2)) * 64);                   \
        BCUR[c][1] = ldb8(bp[c] + ((size_t)((T) + 2)) * 64 + 32);              \
      }                                                                        \
    }                                                                          \
    if ((T) + 1 < NT) {                                                        \
      u16x4 pk;                                                                \
      pk[0] = f2b(AOUT[0]); pk[1] = f2b(AOUT[1]);                              \
      pk[2] = f2b(AOUT[2]); pk[3] = f2b(AOUT[3]);                              \
      *reinterpret_cast<u16x4*>(As + ((((T) + 1) & 1) << 10) + swoff) = pk;    \
    }                                                                          \
    KBARRIER();                                                                \
  }

// BM=16, BK=64, 256 threads (4 waves). Wave w computes cols (w*NC+c)*16..+15
// for c in [0,NC). A staged f32->bf16 into XOR-swizzled LDS (16B-chunk swizzle
// breaks the 128B-row-stride bank conflict). B read direct global->reg from
// B^T layout (rows contiguous in K), depth-2.
template<int NT, int NC, int LDA_, int LDB_>
__device__ __forceinline__ void gemm16(const float* __restrict__ Ab,
                                       const unsigned short* __restrict__ Bt,
                                       unsigned short* As,       // [2*1024]
                                       f32x4 (&acc)[NC], int tid)
{
  const int lane = tid & 63;
  const int wave = tid >> 6;
  const int l15 = lane & 15, lg = lane >> 4;
  const int srow = tid >> 4;          // 0..15
  const int sc4  = (tid & 15) * 4;    // 0..60
  const float* ap = Ab + (size_t)srow * LDA_ + sc4;
  const int swoff = (srow * 64 + sc4) ^ ((srow & 7) << 3);
  const unsigned short* bp[NC];
#pragma unroll
  for (int c = 0; c < NC; ++c)
    bp[c] = Bt + (size_t)((wave * NC + c) * 16 + l15) * LDB_ + lg * 8;
  const int aoff0 = (l15 * 64 + 0 * 32 + lg * 8) ^ ((l15 & 7) << 3);
  const int aoff1 = (l15 * 64 + 1 * 32 + lg * 8) ^ ((l15 & 7) << 3);

  f32x4 aX, aY;
  bf16x8 bA[NC][2], bB[NC][2];

  // prologue: A[0] staged to LDS[0]; A[1] in aX; B[0] in bA, B[1] in bB
  {
    f32x4 a0 = *reinterpret_cast<const f32x4*>(ap);
    aX = *reinterpret_cast<const f32x4*>(ap + 64);
#pragma unroll
    for (int c = 0; c < NC; ++c) {
      bA[c][0] = ldb8(bp[c]);      bA[c][1] = ldb8(bp[c] + 32);
      bB[c][0] = ldb8(bp[c] + 64); bB[c][1] = ldb8(bp[c] + 96);
    }
    u16x4 pk;
    pk[0] = f2b(a0[0]); pk[1] = f2b(a0[1]); pk[2] = f2b(a0[2]); pk[3] = f2b(a0[3]);
    *reinterpret_cast<u16x4*>(As + swoff) = pk;
    KBARRIER();
  }

  for (int t = 0; t < NT; t += 2) {
    GITER(t,     aX, aY, bA);
    GITER(t + 1, aY, aX, bB);
  }
}

// K0: W1t[n][k] = bf16(W1[k][n]), [128][512]
__global__ __launch_bounds__(256) void k0_w1t(const float* __restrict__ W1,
                                              unsigned short* __restrict__ W1t)
{
  int id = blockIdx.x * 256 + threadIdx.x;
  int k = id >> 7, n = id & 127;
  W1t[n * KFEAT + k] = f2b(W1[k * HID + n]);
}

// K1: support_t[c][m] = (x @ W1)[m][c], bf16 [128][8192]
__global__ __launch_bounds__(256) void k1_support(const float* __restrict__ X,
                                                  const unsigned short* __restrict__ W1t,
                                                  unsigned short* __restrict__ St)
{
  __shared__ unsigned short As[2 * 1024];
  const int tid = threadIdx.x;
  const int m0 = blockIdx.x * 16;
  f32x4 acc[2] = {};
  constexpr int NT = KFEAT / 64, NC = 2;
  gemm16<NT, NC, KFEAT, KFEAT>(X + (size_t)m0 * KFEAT, W1t, As, acc, tid);
  const int lane = tid & 63, wave = tid >> 6;
  const int l15 = lane & 15, lg = lane >> 4;
#pragma unroll
  for (int c = 0; c < 2; ++c) {
    int col = (wave * 2 + c) * 16 + l15;
#pragma unroll
    for (int i = 0; i < 4; ++i) {
      int mm = m0 + lg * 4 + i;
      St[(size_t)col * NROW + mm] = f2b(acc[c][i]);
    }
  }
}

// K2: h[m][c] = relu((adj @ support)[m][c] + b1[c]), bf16 [8192][128]
__global__ __launch_bounds__(256) void k2_hidden(const float* __restrict__ ADJ,
                                                 const unsigned short* __restrict__ St,
                                                 const float* __restrict__ b1,
                                                 unsigned short* __restrict__ H)
{
  __shared__ unsigned short As[2 * 1024];
  const int tid = threadIdx.x;
  const int m0 = blockIdx.x * 16;
  f32x4 acc[2] = {};
  constexpr int NT = NROW / 64, NC = 2;
  gemm16<NT, NC, NROW, NROW>(ADJ + (size_t)m0 * NROW, St, As, acc, tid);
  const int lane = tid & 63, wave = tid >> 6;
  const int l15 = lane & 15, lg = lane >> 4;
#pragma unroll
  for (int c = 0; c < 2; ++c) {
    int col = (wave * 2 + c) * 16 + l15;
    float bias = b1[col];
#pragma unroll
    for (int i = 0; i < 4; ++i) {
      int mm = m0 + lg * 4 + i;
      float v = acc[c][i] + bias;
      v = v > 0.f ? v : 0.f;
      H[(size_t)mm * HID + col] = f2b(v);
    }
  }
}

// K3: s2_t[c][m] = (h @ W2)[m][c], bf16 [64][8192], cols 40..63 zero pad
__global__ __launch_bounds__(256) void k3_s2(const unsigned short* __restrict__ H,
                                             const float* __restrict__ W2,
                                             unsigned short* __restrict__ S2t)
{
  __shared__ unsigned short W2t[64 * 136];
  const int tid = threadIdx.x;
  {
    const int n = tid >> 2;
    const int ks = (tid & 3) * 32;
    for (int j = 0; j < 32; ++j) {
      int k = ks + j;
      float v = (n < NCLS) ? W2[k * NCLS + n] : 0.f;
      W2t[n * 136 + k] = f2b(v);
    }
  }
  __syncthreads();
  const int lane = tid & 63, wave = tid >> 6;
  const int l15 = lane & 15, lg = lane >> 4;
  const int m0 = blockIdx.x * 64;
  const int rowm = m0 + wave * 16 + l15;
  f32x4 acc[4] = {};
#pragma unroll
  for (int kk = 0; kk < 4; ++kk) {
    bf16x8 af = *reinterpret_cast<const bf16x8*>(H + (size_t)rowm * HID + kk * 32 + lg * 8);
#pragma unroll
    for (int n = 0; n < 4; ++n) {
      bf16x8 bf = *reinterpret_cast<const bf16x8*>(&W2t[(n * 16 + l15) * 136 + kk * 32 + lg * 8]);
      acc[n] = __builtin_amdgcn_mfma_f32_16x16x32_bf16(af, bf, acc[n], 0, 0, 0);
    }
  }
#pragma unroll
  for (int n = 0; n < 4; ++n)
#pragma unroll
    for (int i = 0; i < 4; ++i) {
      int col = n * 16 + l15;
      int mm = m0 + wave * 16 + lg * 4 + i;
      S2t[(size_t)col * NROW + mm] = f2b(acc[n][i]);
    }
}

// K4: logits = adj @ s2 + b2; out = log_softmax(logits), f32 [8192][40]
__global__ __launch_bounds__(256) void k4_out(const float* __restrict__ ADJ,
                                              const unsigned short* __restrict__ S2t,
                                              const float* __restrict__ b2,
                                              float* __restrict__ OUT)
{
  __shared__ unsigned short As[2 * 1024];
  __shared__ float Ll[16 * 65];
  const int tid = threadIdx.x;
  const int m0 = blockIdx.x * 16;
  f32x4 acc[1] = {};
  constexpr int NT = NROW / 64, NC = 1;
  gemm16<NT, NC, NROW, NROW>(ADJ + (size_t)m0 * NROW, S2t, As, acc, tid);
  const int lane = tid & 63, wave = tid >> 6;
  const int l15 = lane & 15, lg = lane >> 4;
  const int col = wave * 16 + l15;
  if (col < NCLS) {
    const float bias = b2[col];
#pragma unroll
    for (int i = 0; i < 4; ++i) {
      int row = lg * 4 + i;
      Ll[row * 65 + col] = acc[0][i] + bias;
    }
  }
  __syncthreads();
  const int row = tid >> 4;   // 0..15
  const int sub = tid & 15;
  float vals[3];
  int nc = 0;
  float mx = -3.4e38f;
  for (int c = sub; c < NCLS; c += 16) {
    float v = Ll[row * 65 + c];
    vals[nc++] = v;
    mx = fmaxf(mx, v);
  }
#pragma unroll
  for (int d = 1; d < 16; d <<= 1) mx = fmaxf(mx, __shfl_xor(mx, d));
  float se = 0.f;
  for (int j = 0; j < nc; ++j) se += expf(vals[j] - mx);
#pragma unroll
  for (int d = 1; d < 16; d <<= 1) se += __shfl_xor(se, d);
  const float lse = mx + logf(se);
  int j = 0;
  for (int c = sub; c < NCLS; c += 16) {
    OUT[(size_t)(m0 + row) * NCLS + c] = vals[j++] - lse;
  }
}

extern "C" void kernel_launch(void* const* d_in, const int* in_sizes, int n_in,
                              void* d_out, int out_size, void* d_ws, size_t ws_size,
                              hipStream_t stream)
{
  const float* x   = (const float*)d_in[0];
  const float* adj = (const float*)d_in[1];
  const float* W1  = (const float*)d_in[2];
  const float* b1  = (const float*)d_in[3];
  const float* W2  = (const float*)d_in[4];
  const float* b2  = (const float*)d_in[5];
  float* out = (float*)d_out;

  char* ws = (char*)d_ws;
  unsigned short* W1t = (unsigned short*)(ws);                          // 128KB
  unsigned short* St  = (unsigned short*)(ws + 131072);                 // 2MB
  unsigned short* H   = (unsigned short*)(ws + 131072 + 2097152);       // 2MB
  unsigned short* S2t = (unsigned short*)(ws + 131072 + 2 * 2097152);   // 1MB

  hipLaunchKernelGGL(k0_w1t,     dim3(256), dim3(256), 0, stream, W1, W1t);
  hipLaunchKernelGGL(k1_support, dim3(512), dim3(256), 0, stream, x, W1t, St);
  hipLaunchKernelGGL(k2_hidden,  dim3(512), dim3(256), 0, stream, adj, St, b1, H);
  hipLaunchKernelGGL(k3_s2,      dim3(128), dim3(256), 0, stream, H, W2, S2t);
  hipLaunchKernelGGL(k4_out,     dim3(512), dim3(256), 0, stream, adj, S2t, b2, out);
}

// Round 3
// 179.433 us; speedup vs baseline: 1.3923x; 1.3923x over previous
//
#include <hip/hip_runtime.h>

// GCN forward on MI355X:
//   out = log_softmax(adj @ (relu(adj @ (x@W1) + b1) @ W2) + b2)
// N=8192, NFEAT=512, NHID=128, NCLASS=40. adj is 256MB f32, read twice.
// bf16 MFMA 16x16x32. adj converted f32->bf16 on the fly via swizzled LDS.
// B operands stored FRAGMENT-LINEAR: Bf[ct][kb][lane][8] so each wave's
// B-fragment load is one contiguous 1KB ldb8 (fixes round-2's 16-line-scatter
// B loads that stalled k2 at 10% BW). Raw s_barrier (lgkmcnt(0) only, no
// vmcnt drain), depth-2 register prefetch for A (HBM) and B (L2).
// BM=16 rows/block, 256 threads (4 waves), grid 512 = 2 blocks/CU.

using bf16x8 = __attribute__((ext_vector_type(8))) __bf16;
using f32x4  = __attribute__((ext_vector_type(4))) float;
using u16x4  = __attribute__((ext_vector_type(4))) unsigned short;
using u16x8  = __attribute__((ext_vector_type(8))) unsigned short;

#define NROW 8192
#define KFEAT 512
#define HID 128
#define NCLS 40

__device__ __forceinline__ unsigned short f2b(float f) {
  union { float f; unsigned u; } v; v.f = f;
  unsigned r = v.u + 0x7fffu + ((v.u >> 16) & 1u);
  return (unsigned short)(r >> 16);
}

__device__ __forceinline__ bf16x8 ldb8(const unsigned short* p) {
  return *reinterpret_cast<const bf16x8*>(p);
}

#define KBARRIER()                                        \
  asm volatile("s_waitcnt lgkmcnt(0)" ::: "memory");      \
  __builtin_amdgcn_s_barrier();                           \
  asm volatile("" ::: "memory");                          \
  __builtin_amdgcn_sched_barrier(0)

// One K-tile iteration. AOUT: regs holding A[T+1] (cvt+LDS-write this iter).
// APRE: regs to receive A[T+2]. BCUR: B[T] (consumed, then refilled with B[T+2]).
// LDS: read buf[T&1], write buf[(T+1)&1]; single barrier per tile is safe
// (disjoint buffers; s_barrier keeps all waves within one tile of each other).
#define GITER(T, AOUT, APRE, BCUR)                                             \
  {                                                                            \
    if ((T) + 2 < NT) {                                                        \
      APRE = *reinterpret_cast<const f32x4*>(ap + ((size_t)((T) + 2)) * 64);   \
    }                                                                          \
    const unsigned short* lb = As + (((T) & 1) << 10);                         \
    _Pragma("unroll")                                                          \
    for (int s = 0; s < 2; ++s) {                                              \
      bf16x8 af = *reinterpret_cast<const bf16x8*>(lb + (s ? aoff1 : aoff0));  \
      _Pragma("unroll")                                                        \
      for (int c = 0; c < NC; ++c)                                             \
        acc[c] = __builtin_amdgcn_mfma_f32_16x16x32_bf16(af, BCUR[c][s],       \
                                                         acc[c], 0, 0, 0);    \
    }                                                                          \
    if ((T) + 2 < NT) {                                                        \
      _Pragma("unroll")                                                        \
      for (int c = 0; c < NC; ++c) {                                           \
        BCUR[c][0] = ldb8(bp[c] + ((size_t)((T) + 2)) * 1024);                 \
        BCUR[c][1] = ldb8(bp[c] + ((size_t)((T) + 2)) * 1024 + 512);           \
      }                                                                        \
    }                                                                          \
    if ((T) + 1 < NT) {                                                        \
      u16x4 pk;                                                                \
      pk[0] = f2b(AOUT[0]); pk[1] = f2b(AOUT[1]);                              \
      pk[2] = f2b(AOUT[2]); pk[3] = f2b(AOUT[3]);                              \
      *reinterpret_cast<u16x4*>(As + ((((T) + 1) & 1) << 10) + swoff) = pk;    \
    }                                                                          \
    KBARRIER();                                                                \
  }

// BM=16, BK=64, 256 threads (4 waves). Wave w covers col-tiles ct = w*NC+c.
// A: f32 global -> bf16 -> XOR-swizzled LDS (zero bank conflicts).
// B: fragment-linear global, contiguous 16B/lane loads, depth-2 prefetch.
template<int NT, int NC, int LDA_>
__device__ __forceinline__ void gemm16f(const float* __restrict__ Ab,
                                        const unsigned short* __restrict__ Bf,
                                        unsigned short* As,      // [2*1024]
                                        f32x4 (&acc)[NC], int tid)
{
  const int lane = tid & 63;
  const int wave = tid >> 6;
  const int l15 = lane & 15, lg = lane >> 4;
  const int srow = tid >> 4;          // 0..15
  const int sc4  = (tid & 15) * 4;    // 0..60
  const float* ap = Ab + (size_t)srow * LDA_ + sc4;
  const int swoff = (srow * 64 + sc4) ^ ((srow & 7) << 3);
  const unsigned short* bp[NC];
#pragma unroll
  for (int c = 0; c < NC; ++c)
    bp[c] = Bf + (size_t)(wave * NC + c) * (NT * 2) * 512 + lane * 8;
  const int aoff0 = (l15 * 64 + lg * 8) ^ ((l15 & 7) << 3);
  const int aoff1 = (l15 * 64 + 32 + lg * 8) ^ ((l15 & 7) << 3);

  f32x4 aX, aY;
  bf16x8 bA[NC][2], bB[NC][2];

  // prologue: A[0]->LDS[0]; A[1]->aX; B[0]->bA, B[1]->bB
  {
    f32x4 a0 = *reinterpret_cast<const f32x4*>(ap);
    aX = *reinterpret_cast<const f32x4*>(ap + 64);
#pragma unroll
    for (int c = 0; c < NC; ++c) {
      bA[c][0] = ldb8(bp[c]);        bA[c][1] = ldb8(bp[c] + 512);
      bB[c][0] = ldb8(bp[c] + 1024); bB[c][1] = ldb8(bp[c] + 1536);
    }
    u16x4 pk;
    pk[0] = f2b(a0[0]); pk[1] = f2b(a0[1]); pk[2] = f2b(a0[2]); pk[3] = f2b(a0[3]);
    *reinterpret_cast<u16x4*>(As + swoff) = pk;
    KBARRIER();
  }

  for (int t = 0; t < NT; t += 2) {
    GITER(t,     aX, aY, bA);
    GITER(t + 1, aY, aX, bB);
  }
}

// K0: W1f fragment-linear from W1[512][128]. KB=16 (K=512).
// Element (col,k): offset ((ct*16+kb)*64 + (col&15) + 16*((k>>3)&3))*8 + (k&7).
// One thread per 16B chunk: 8192 threads.
__global__ __launch_bounds__(256) void k0_w1f(const float* __restrict__ W1,
                                              unsigned short* __restrict__ W1f)
{
  int id = blockIdx.x * 256 + threadIdx.x;   // 0..8191
  int l16 = id & 63, blkid = id >> 6;        // blkid 0..127
  int kb = blkid & 15, ct = blkid >> 4;
  int c = ct * 16 + (l16 & 15);
  int k0 = kb * 32 + (l16 >> 4) * 8;
  u16x8 pk;
#pragma unroll
  for (int j = 0; j < 8; ++j) pk[j] = f2b(W1[(size_t)(k0 + j) * HID + c]);
  *reinterpret_cast<u16x8*>(W1f + (size_t)id * 8) = pk;
}

// K1: support = x @ W1 -> Stf fragment-linear (KB=256, K dim = row m).
__global__ __launch_bounds__(256) void k1_support(const float* __restrict__ X,
                                                  const unsigned short* __restrict__ W1f,
                                                  unsigned short* __restrict__ Stf)
{
  __shared__ unsigned short As[2 * 1024];
  const int tid = threadIdx.x;
  const int blk = blockIdx.x;
  const int m0 = blk * 16;
  f32x4 acc[2] = {};
  constexpr int NT = KFEAT / 64, NC = 2;
  gemm16f<NT, NC, KFEAT>(X + (size_t)m0 * KFEAT, W1f, As, acc, tid);
  const int lane = tid & 63, wave = tid >> 6;
  const int l15 = lane & 15, lg = lane >> 4;
  // acc[c][i] = support[m][col], m = m0+lg*4+i, col = (wave*2+c)*16+l15.
  // Fragment-linear store: kb=m>>5, lgc=(m&31)>>3, j=m&7 -> contiguous i.
  const int kb  = blk >> 1;
  const int lgc = ((blk & 1) << 1) + (lg >> 1);
  const int jb  = (lg & 1) * 4;
#pragma unroll
  for (int c = 0; c < 2; ++c) {
    int ctc = wave * 2 + c;
    u16x4 pk;
#pragma unroll
    for (int i = 0; i < 4; ++i) pk[i] = f2b(acc[c][i]);
    *reinterpret_cast<u16x4*>(Stf + (size_t)(ctc * 256 + kb) * 512 +
                              (l15 + 16 * lgc) * 8 + jb) = pk;
  }
}

// K2: h = relu(adj @ support + b1), row-major bf16 H[8192][128]
__global__ __launch_bounds__(256) void k2_hidden(const float* __restrict__ ADJ,
                                                 const unsigned short* __restrict__ Stf,
                                                 const float* __restrict__ b1,
                                                 unsigned short* __restrict__ H)
{
  __shared__ unsigned short As[2 * 1024];
  const int tid = threadIdx.x;
  const int m0 = blockIdx.x * 16;
  f32x4 acc[2] = {};
  constexpr int NT = NROW / 64, NC = 2;
  gemm16f<NT, NC, NROW>(ADJ + (size_t)m0 * NROW, Stf, As, acc, tid);
  const int lane = tid & 63, wave = tid >> 6;
  const int l15 = lane & 15, lg = lane >> 4;
#pragma unroll
  for (int c = 0; c < 2; ++c) {
    int col = (wave * 2 + c) * 16 + l15;
    float bias = b1[col];
#pragma unroll
    for (int i = 0; i < 4; ++i) {
      int mm = m0 + lg * 4 + i;
      float v = acc[c][i] + bias;
      v = v > 0.f ? v : 0.f;
      H[(size_t)mm * HID + col] = f2b(v);
    }
  }
}

// K3: s2 = h @ W2 -> S2f fragment-linear (64 cols, 40..63 zero-padded; KB=256)
__global__ __launch_bounds__(256) void k3_s2(const unsigned short* __restrict__ H,
                                             const float* __restrict__ W2,
                                             unsigned short* __restrict__ S2f)
{
  __shared__ unsigned short W2t[64 * 136];
  const int tid = threadIdx.x;
  {
    const int n = tid >> 2;
    const int ks = (tid & 3) * 32;
    for (int j = 0; j < 32; ++j) {
      int k = ks + j;
      float v = (n < NCLS) ? W2[k * NCLS + n] : 0.f;
      W2t[n * 136 + k] = f2b(v);
    }
  }
  __syncthreads();
  const int lane = tid & 63, wave = tid >> 6;
  const int l15 = lane & 15, lg = lane >> 4;
  const int blk = blockIdx.x;
  const int m0 = blk * 64;
  const int rowm = m0 + wave * 16 + l15;
  f32x4 acc[4] = {};
#pragma unroll
  for (int kk = 0; kk < 4; ++kk) {
    bf16x8 af = *reinterpret_cast<const bf16x8*>(H + (size_t)rowm * HID + kk * 32 + lg * 8);
#pragma unroll
    for (int n = 0; n < 4; ++n) {
      bf16x8 bf = *reinterpret_cast<const bf16x8*>(&W2t[(n * 16 + l15) * 136 + kk * 32 + lg * 8]);
      acc[n] = __builtin_amdgcn_mfma_f32_16x16x32_bf16(af, bf, acc[n], 0, 0, 0);
    }
  }
  // acc[n][i] = s2[m][col], m = m0 + wave*16 + lg*4 + i, col = n*16+l15.
  const int kb  = blk * 2 + (wave >> 1);
  const int lgc = ((wave & 1) << 1) + (lg >> 1);
  const int jb  = (lg & 1) * 4;
#pragma unroll
  for (int n = 0; n < 4; ++n) {
    u16x4 pk;
#pragma unroll
    for (int i = 0; i < 4; ++i) pk[i] = f2b(acc[n][i]);
    *reinterpret_cast<u16x4*>(S2f + (size_t)(n * 256 + kb) * 512 +
                              (l15 + 16 * lgc) * 8 + jb) = pk;
  }
}

// K4: logits = adj @ s2 + b2; out = log_softmax(logits), f32 [8192][40]
__global__ __launch_bounds__(256) void k4_out(const float* __restrict__ ADJ,
                                              const unsigned short* __restrict__ S2f,
                                              const float* __restrict__ b2,
                                              float* __restrict__ OUT)
{
  __shared__ unsigned short As[2 * 1024];
  __shared__ float Ll[16 * 65];
  const int tid = threadIdx.x;
  const int m0 = blockIdx.x * 16;
  f32x4 acc[1] = {};
  constexpr int NT = NROW / 64, NC = 1;
  gemm16f<NT, NC, NROW>(ADJ + (size_t)m0 * NROW, S2f, As, acc, tid);
  const int lane = tid & 63, wave = tid >> 6;
  const int l15 = lane & 15, lg = lane >> 4;
  const int col = wave * 16 + l15;
  if (col < NCLS) {
    const float bias = b2[col];
#pragma unroll
    for (int i = 0; i < 4; ++i) {
      int row = lg * 4 + i;
      Ll[row * 65 + col] = acc[0][i] + bias;
    }
  }
  __syncthreads();
  const int row = tid >> 4;   // 0..15
  const int sub = tid & 15;
  float vals[3];
  int nc = 0;
  float mx = -3.4e38f;
  for (int c = sub; c < NCLS; c += 16) {
    float v = Ll[row * 65 + c];
    vals[nc++] = v;
    mx = fmaxf(mx, v);
  }
#pragma unroll
  for (int d = 1; d < 16; d <<= 1) mx = fmaxf(mx, __shfl_xor(mx, d));
  float se = 0.f;
  for (int j = 0; j < nc; ++j) se += expf(vals[j] - mx);
#pragma unroll
  for (int d = 1; d < 16; d <<= 1) se += __shfl_xor(se, d);
  const float lse = mx + logf(se);
  int j = 0;
  for (int c = sub; c < NCLS; c += 16) {
    OUT[(size_t)(m0 + row) * NCLS + c] = vals[j++] - lse;
  }
}

extern "C" void kernel_launch(void* const* d_in, const int* in_sizes, int n_in,
                              void* d_out, int out_size, void* d_ws, size_t ws_size,
                              hipStream_t stream)
{
  const float* x   = (const float*)d_in[0];
  const float* adj = (const float*)d_in[1];
  const float* W1  = (const float*)d_in[2];
  const float* b1  = (const float*)d_in[3];
  const float* W2  = (const float*)d_in[4];
  const float* b2  = (const float*)d_in[5];
  float* out = (float*)d_out;

  char* ws = (char*)d_ws;
  unsigned short* W1f = (unsigned short*)(ws);                          // 128KB
  unsigned short* Stf = (unsigned short*)(ws + 131072);                 // 2MB
  unsigned short* H   = (unsigned short*)(ws + 131072 + 2097152);       // 2MB
  unsigned short* S2f = (unsigned short*)(ws + 131072 + 2 * 2097152);   // 1MB

  hipLaunchKernelGGL(k0_w1f,     dim3(32),  dim3(256), 0, stream, W1, W1f);
  hipLaunchKernelGGL(k1_support, dim3(512), dim3(256), 0, stream, x, W1f, Stf);
  hipLaunchKernelGGL(k2_hidden,  dim3(512), dim3(256), 0, stream, adj, Stf, b1, H);
  hipLaunchKernelGGL(k3_s2,      dim3(128), dim3(256), 0, stream, H, W2, S2f);
  hipLaunchKernelGGL(k4_out,     dim3(512), dim3(256), 0, stream, adj, S2f, b2, out);
}